// Round 1
// baseline (75.577 us; speedup 1.0000x reference)
//
#include <hip/hip_runtime.h>

// KAN 2x2 convolution, stride 1, summed over C input channels.
// x: (B=8, C=16, H=128, W=128) fp32 -> out: (B, 1, H-1, W-1) fp32
//
// Key idea: the knot grid is uniform (h = g[1]-g[0]), so the Cox-de-Boor
// cubic bases reduce to the 4 uniform cubic B-spline blending polynomials.
// For each knot interval t (0..10) and patch position p (0..3) we fold
// blending matrix x scaled spline weights into cubic coefficients (c0..c3):
//   spline_contrib(x) = c0 + u*(c1 + u*(c2 + u*c3)),  u = (x-g[t])/h
// Table: 11*4 float4 = 704 B in LDS, built once per block.

#define KH 2
#define KW 2
#define IN_F 4
#define N_COEF 8
#define N_INTERVALS 11  // n_knots - 1

__device__ __forceinline__ float silu(float x) {
    // x * sigmoid(x) = x / (1 + exp(-x))
    return x * __builtin_amdgcn_rcpf(1.0f + __expf(-x));
}

__global__ __launch_bounds__(256) void kan_conv_kernel(
    const float* __restrict__ x,
    const float* __restrict__ base_w,    // (1,4)
    const float* __restrict__ spline_w,  // (1,4,8)
    const float* __restrict__ spline_s,  // (1,4)
    const float* __restrict__ grid,      // (4,12), identical rows, uniform
    float* __restrict__ out,
    int B, int C, int H, int W)
{
    const int Ho = H - 1, Wo = W - 1;

    __shared__ float4 coef[N_INTERVALS][IN_F];  // [t][p] -> (c0,c1,c2,c3)
    __shared__ float s_bw[IN_F];
    __shared__ float s_g0, s_invh;

    const int tid = threadIdx.x;
    if (tid < N_INTERVALS * IN_F) {
        const int t = tid / IN_F;
        const int p = tid % IN_F;
        // uniform cubic B-spline blending, power basis coeffs of (1,u,u^2,u^3):
        // m=0 (basis j=t-3): (1,-3, 3,-1)/6
        // m=1 (basis j=t-2): (4, 0,-6, 3)/6
        // m=2 (basis j=t-1): (1, 3, 3,-3)/6
        // m=3 (basis j=t  ): (0, 0, 0, 1)/6
        const float M[4][4] = {
            {1.f/6.f, -3.f/6.f,  3.f/6.f, -1.f/6.f},
            {4.f/6.f,  0.f,     -6.f/6.f,  3.f/6.f},
            {1.f/6.f,  3.f/6.f,  3.f/6.f, -3.f/6.f},
            {0.f,      0.f,      0.f,      1.f/6.f}};
        const float scal = spline_s[p];
        float c0 = 0.f, c1 = 0.f, c2 = 0.f, c3 = 0.f;
        #pragma unroll
        for (int m = 0; m < 4; ++m) {
            const int j = t - 3 + m;
            const float w = (j >= 0 && j < N_COEF)
                              ? spline_w[p * N_COEF + j] * scal : 0.f;
            c0 += M[m][0] * w; c1 += M[m][1] * w;
            c2 += M[m][2] * w; c3 += M[m][3] * w;
        }
        coef[t][p] = make_float4(c0, c1, c2, c3);
    }
    if (tid < IN_F) s_bw[tid] = base_w[tid];
    if (tid == 0) { s_g0 = grid[0]; s_invh = 1.0f / (grid[1] - grid[0]); }
    __syncthreads();

    const float g0 = s_g0, invh = s_invh;
    const float bw0 = s_bw[0], bw1 = s_bw[1], bw2 = s_bw[2], bw3 = s_bw[3];

    const int total = B * Ho * Wo;
    const int HW = H * W;

    for (int o = blockIdx.x * blockDim.x + tid; o < total;
         o += gridDim.x * blockDim.x) {
        const int wo = o % Wo;
        const int rest = o / Wo;
        const int ho = rest % Ho;
        const int b = rest / Ho;

        const float* xb = x + (size_t)b * C * HW + (size_t)ho * W + wo;

        float acc = 0.f;
        #pragma unroll 4
        for (int c = 0; c < 16; ++c) {
            const float* xc = xb + (size_t)c * HW;
            const float v00 = xc[0];
            const float v01 = xc[1];
            const float v10 = xc[W];
            const float v11 = xc[W + 1];

            // base (SiLU) path — always applies
            acc += silu(v00) * bw0 + silu(v01) * bw1 +
                   silu(v10) * bw2 + silu(v11) * bw3;

            // spline path — vanish outside the extended knot range
            #pragma unroll
            for (int p = 0; p < 4; ++p) {
                const float v = (p == 0) ? v00 : (p == 1) ? v01
                              : (p == 2) ? v10 : v11;
                const float tf = (v - g0) * invh;
                const float tfl = floorf(tf);
                const int ti = (int)tfl;
                if ((unsigned)ti < (unsigned)N_INTERVALS) {
                    const float u = tf - tfl;
                    const float4 cf = coef[ti][p];
                    float sp = fmaf(u, cf.w, cf.z);
                    sp = fmaf(u, sp, cf.y);
                    sp = fmaf(u, sp, cf.x);
                    acc += sp;
                }
            }
        }
        out[o] = acc;
    }
}

extern "C" void kernel_launch(void* const* d_in, const int* in_sizes, int n_in,
                              void* d_out, int out_size, void* d_ws, size_t ws_size,
                              hipStream_t stream) {
    const float* x        = (const float*)d_in[0];
    const float* base_w   = (const float*)d_in[1];
    const float* spline_w = (const float*)d_in[2];
    const float* spline_s = (const float*)d_in[3];
    const float* grid     = (const float*)d_in[4];
    float* out = (float*)d_out;

    const int B = 8, C = 16, H = 128, W = 128;
    const int total = B * (H - 1) * (W - 1);
    const int threads = 256;
    const int blocks = (total + threads - 1) / threads;

    kan_conv_kernel<<<blocks, threads, 0, stream>>>(
        x, base_w, spline_w, spline_s, grid, out, B, C, H, W);
}

// Round 2
// 75.242 us; speedup vs baseline: 1.0045x; 1.0045x over previous
//
#include <hip/hip_runtime.h>

// KAN 2x2 convolution, stride 1, summed over C=16 input channels.
// x: (8,16,128,128) fp32 -> out: (8,1,127,127) fp32
//
// Round-2 structure:
//  - uniform-knot cubic B-spline folded into per-(interval,position) cubic
//    coefficient table (11x4 float4, LDS), as in round 1 (exact reformulation)
//  - block = 256 threads handles a 32x8 output tile for a group of 4 channels
//    -> 2048 blocks (8 waves/SIMD vs round-1's 2) for latency hiding
//  - per channel: phase A evaluates each of the 33x9 input values ONCE
//    (silu + interval + 4 Horner dot-products) into SoA LDS; phase B gathers
//    the 4 window neighbors. Removes the 4x redundant spline/silu work.
//  - channel-group partials combined via one atomicAdd per output thread;
//    d_out zeroed by hipMemsetAsync (memset node, graph-capture safe).

#define IN_F 4
#define N_COEF 8
#define N_INT 11   // knot intervals
#define TW 32      // output tile width
#define TH 8       // output tile height
#define LW 33      // input tile width  (TW+1)
#define LH 9       // input tile height (TH+1)
#define NV (LW * LH)  // 297 input values per tile
#define CG 4       // channels per block

__device__ __forceinline__ float silu(float x) {
    return x * __builtin_amdgcn_rcpf(1.0f + __expf(-x));
}

__global__ __launch_bounds__(256) void kan_conv_kernel(
    const float* __restrict__ x,
    const float* __restrict__ base_w,    // (1,4)
    const float* __restrict__ spline_w,  // (1,4,8)
    const float* __restrict__ spline_s,  // (1,4)
    const float* __restrict__ grid,      // (4,12) identical uniform rows
    float* __restrict__ out,
    int B, int C, int H, int W)
{
    const int Ho = H - 1, Wo = W - 1;

    __shared__ float4 coef[N_INT][IN_F];   // [t][p] -> cubic coeffs (c0..c3)
    __shared__ float  sfeat[IN_F][NV];     // per-position features, SoA
    __shared__ float  s_misc[6];           // bw0..bw3, g0, invh

    const int tid = threadIdx.x;

    // ---- one-time table build (tid 0..48) ----
    if (tid < N_INT * IN_F) {
        const int t = tid / IN_F;
        const int p = tid % IN_F;
        // uniform cubic B-spline blending matrix (power basis in u)
        const float M[4][4] = {
            {1.f/6.f, -3.f/6.f,  3.f/6.f, -1.f/6.f},
            {4.f/6.f,  0.f,     -6.f/6.f,  3.f/6.f},
            {1.f/6.f,  3.f/6.f,  3.f/6.f, -3.f/6.f},
            {0.f,      0.f,      0.f,      1.f/6.f}};
        const float scal = spline_s[p];
        float c0 = 0.f, c1 = 0.f, c2 = 0.f, c3 = 0.f;
        #pragma unroll
        for (int m = 0; m < 4; ++m) {
            const int j = t - 3 + m;
            const float w = (j >= 0 && j < N_COEF)
                              ? spline_w[p * N_COEF + j] * scal : 0.f;
            c0 += M[m][0] * w; c1 += M[m][1] * w;
            c2 += M[m][2] * w; c3 += M[m][3] * w;
        }
        coef[t][p] = make_float4(c0, c1, c2, c3);
    }
    if (tid < IN_F) s_misc[tid] = base_w[tid];
    if (tid == 4)   s_misc[4] = grid[0];
    if (tid == 5)   s_misc[5] = 1.0f / (grid[1] - grid[0]);

    // ---- block decomposition: 4 cgroups x 4 xtiles x 16 ytiles x 8 batches ----
    int bid = blockIdx.x;
    const int cg  = bid & 3;  bid >>= 2;
    const int txi = bid & 3;  bid >>= 2;
    const int tyi = bid & 15; bid >>= 4;
    const int b   = bid;
    const int tx0 = txi * TW, ty0 = tyi * TH, c0ch = cg * CG;

    const int lx = tid & (TW - 1);
    const int ly = tid >> 5;           // 0..7
    const int oy = ty0 + ly, ox = tx0 + lx;

    __syncthreads();
    const float bw0 = s_misc[0], bw1 = s_misc[1];
    const float bw2 = s_misc[2], bw3 = s_misc[3];
    const float g0 = s_misc[4], invh = s_misc[5];
    const float bw[4] = {bw0, bw1, bw2, bw3};

    float acc = 0.f;

    #pragma unroll
    for (int g = 0; g < CG; ++g) {
        const int c = c0ch + g;
        const float* __restrict__ xc = x + ((size_t)(b * C + c) * H) * W;

        if (g > 0) __syncthreads();   // protect LDS overwrite after gather

        // ---- phase A: evaluate each input value once ----
        #pragma unroll
        for (int v = tid; v < NV; v += 256) {
            const int r  = v / LW;
            const int cc = v - r * LW;
            const int iy = ty0 + r, ix = tx0 + cc;
            const float val = (iy < H && ix < W) ? xc[iy * W + ix] : 0.f;

            const float sil = silu(val);
            const float tf  = (val - g0) * invh;
            const float tfl = floorf(tf);
            const int   ti  = (int)tfl;
            const float u   = tf - tfl;
            const bool  valid = ((unsigned)ti < (unsigned)N_INT);
            const int   tc  = valid ? ti : 0;

            #pragma unroll
            for (int p = 0; p < IN_F; ++p) {
                const float4 cf = coef[tc][p];
                float sp = fmaf(u, cf.w, cf.z);
                sp = fmaf(u, sp, cf.y);
                sp = fmaf(u, sp, cf.x);
                sfeat[p][v] = fmaf(sil, bw[p], valid ? sp : 0.f);
            }
        }
        __syncthreads();

        // ---- phase B: gather 4 window neighbors ----
        const int i00 = ly * LW + lx;
        acc += sfeat[0][i00] + sfeat[1][i00 + 1]
             + sfeat[2][i00 + LW] + sfeat[3][i00 + LW + 1];
    }

    if (oy < Ho && ox < Wo)
        atomicAdd(&out[((size_t)b * Ho + oy) * Wo + ox], acc);
}

extern "C" void kernel_launch(void* const* d_in, const int* in_sizes, int n_in,
                              void* d_out, int out_size, void* d_ws, size_t ws_size,
                              hipStream_t stream) {
    const float* x        = (const float*)d_in[0];
    const float* base_w   = (const float*)d_in[1];
    const float* spline_w = (const float*)d_in[2];
    const float* spline_s = (const float*)d_in[3];
    const float* grid     = (const float*)d_in[4];
    float* out = (float*)d_out;

    const int B = 8, C = 16, H = 128, W = 128;

    hipMemsetAsync(out, 0, (size_t)out_size * sizeof(float), stream);

    // 8 batches x 16 ytiles x 4 xtiles x 4 channel-groups = 2048 blocks
    kan_conv_kernel<<<2048, 256, 0, stream>>>(
        x, base_w, spline_w, spline_s, grid, out, B, C, H, W);
}